// Round 5
// baseline (543.180 us; speedup 1.0000x reference)
//
#include <hip/hip_runtime.h>
#include <hip/hip_bf16.h>

#define NN 50000
#define NE 800000
#define DD 128
#define NCLS 40

typedef short bf8 __attribute__((ext_vector_type(8)));   // 8 bf16 (4 VGPRs)
typedef float f32x4 __attribute__((ext_vector_type(4))); // MFMA acc

__device__ __forceinline__ unsigned short f2bf(float x) {
    unsigned int u = __float_as_uint(x);
    unsigned int r = (u + 0x7FFFu + ((u >> 16) & 1u)) >> 16;  // RNE
    return (unsigned short)r;
}
__device__ __forceinline__ float bf2f(unsigned short h) {
    return __uint_as_float(((unsigned int)h) << 16);
}
__device__ __forceinline__ unsigned int packhl(float v) {
    unsigned short h = f2bf(v);
    unsigned short l = f2bf(v - bf2f(h));
    return ((unsigned int)h << 16) | l;
}
__device__ __forceinline__ float unpackhl(unsigned int p) {
    return __uint_as_float(p & 0xFFFF0000u) + __uint_as_float(p << 16);
}

// ---------------------------------------------------------------------------
__global__ void k_detect(const int* __restrict__ ei, int* __restrict__ flag) {
    __shared__ int nz;
    if (threadIdx.x == 0) nz = 0;
    __syncthreads();
    int any = 0;
    for (int e = threadIdx.x; e < 2048; e += 256)
        if (ei[2 * e + 1] != 0) any = 1;
    if (any) atomicOr(&nz, 1);
    __syncthreads();
    if (threadIdx.x == 0) *flag = (nz == 0) ? 1 : 0;  // 1 => int64 layout
}

__global__ void k_zero_int(int* __restrict__ p, int n) {
    int i = blockIdx.x * 256 + threadIdx.x;
    if (i < n) p[i] = 0;
}

__global__ void k_count(const int* __restrict__ ei, const int* __restrict__ flag,
                        int* __restrict__ cnt) {
    int e = blockIdx.x * 256 + threadIdx.x;
    if (e >= NE) return;
    int is64 = *flag;
    int d = is64 ? ei[2 * (NE + e)] : ei[NE + e];
    atomicAdd(&cnt[d], 1);
}

__global__ void k_scan1(const int* __restrict__ cnt, int* __restrict__ incl,
                        int* __restrict__ bsum) {
    __shared__ int s[1024];
    int t = threadIdx.x;
    int i = blockIdx.x * 1024 + t;
    int v = (i < NN) ? cnt[i] : 0;
    s[t] = v;
    __syncthreads();
#pragma unroll
    for (int off = 1; off < 1024; off <<= 1) {
        int u = (t >= off) ? s[t - off] : 0;
        __syncthreads();
        s[t] += u;
        __syncthreads();
    }
    if (i < NN) incl[i] = s[t];
    if (t == 1023) bsum[blockIdx.x] = s[1023];
}

__global__ void k_scan2(int* __restrict__ bsum, int* __restrict__ boff,
                        const int nb) {
    __shared__ int s[64];
    int t = threadIdx.x;
    s[t] = (t < nb) ? bsum[t] : 0;
    __syncthreads();
#pragma unroll
    for (int off = 1; off < 64; off <<= 1) {
        int u = (t >= off) ? s[t - off] : 0;
        __syncthreads();
        s[t] += u;
        __syncthreads();
    }
    if (t < nb) boff[t] = s[t] - bsum[t];
    if (t == 63) boff[nb] = s[63];
}

__global__ void k_scan3(const int* __restrict__ cnt, const int* __restrict__ incl,
                        const int* __restrict__ boff, int* __restrict__ row_ptr,
                        int* __restrict__ cursor, const int nb) {
    int i = blockIdx.x * 1024 + threadIdx.x;
    if (i < NN) {
        row_ptr[i] = incl[i] - cnt[i] + boff[blockIdx.x];
        cursor[i] = 0;
    }
    if (i == 0) row_ptr[NN] = boff[nb];
}

__global__ void k_fill(const int* __restrict__ ei, const int* __restrict__ flag,
                       const int* __restrict__ row_ptr, int* __restrict__ cursor,
                       int* __restrict__ srcs) {
    int e = blockIdx.x * 256 + threadIdx.x;
    if (e >= NE) return;
    int is64 = *flag;
    int s, d;
    if (is64) { s = ei[2 * e]; d = ei[2 * (NE + e)]; }
    else      { s = ei[e];     d = ei[NE + e]; }
    int pos = row_ptr[d] + atomicAdd(&cursor[d], 1);
    srcs[pos] = s;
}

// ---------------------------------------------------------------------------
// fp32 -> packed (hi<<16 | lo). 50000*128/4 float4 -> uint4.
__global__ void k_cvt_x(const float* __restrict__ x, unsigned int* __restrict__ xp) {
    int i = blockIdx.x * 256 + threadIdx.x;
    float4 v = ((const float4*)x)[i];
    uint4 o;
    o.x = packhl(v.x); o.y = packhl(v.y); o.z = packhl(v.z); o.w = packhl(v.w);
    ((uint4*)xp)[i] = o;
}

// Build Bt[n][k] (n-major, k over [Wl;Wr]), separate hi/lo, zero pad n>=NC.
__global__ void k_cvt_w(const float* __restrict__ wl, const float* __restrict__ wr,
                        unsigned short* __restrict__ bth, unsigned short* __restrict__ btl,
                        const int NC) {
    int n = blockIdx.x;
    int k = threadIdx.x;
    float v = 0.f;
    if (n < NC)
        v = (k < 128) ? wl[(size_t)k * NC + n] : wr[(size_t)(k - 128) * NC + n];
    unsigned short h = f2bf(v);
    unsigned short l = f2bf(v - bf2f(h));
    bth[(size_t)n * 256 + k] = h;
    btl[(size_t)n * 256 + k] = l;
}

// ---------------------------------------------------------------------------
// Mean aggregation: one wave per node, uint2 per lane (full 512B row/neighbor).
// 256-thread block covers 4 nodes.
__global__ void k_agg(const unsigned int* __restrict__ in, const int* __restrict__ row_ptr,
                      const int* __restrict__ srcs, unsigned int* __restrict__ o) {
    int node = blockIdx.x * 4 + (threadIdx.x >> 6);
    if (node >= NN) return;
    int lane = threadIdx.x & 63;
    int b = row_ptr[node], e = row_ptr[node + 1];
    float a0 = 0.f, a1 = 0.f;
    int i = b;
    for (; i + 3 < e; i += 4) {
        int s0 = srcs[i + 0], s1 = srcs[i + 1], s2 = srcs[i + 2], s3 = srcs[i + 3];
        uint2 p0 = *(const uint2*)(in + (size_t)s0 * DD + lane * 2);
        uint2 p1 = *(const uint2*)(in + (size_t)s1 * DD + lane * 2);
        uint2 p2 = *(const uint2*)(in + (size_t)s2 * DD + lane * 2);
        uint2 p3 = *(const uint2*)(in + (size_t)s3 * DD + lane * 2);
        a0 += unpackhl(p0.x) + unpackhl(p1.x) + unpackhl(p2.x) + unpackhl(p3.x);
        a1 += unpackhl(p0.y) + unpackhl(p1.y) + unpackhl(p2.y) + unpackhl(p3.y);
    }
    for (; i < e; ++i) {
        uint2 p = *(const uint2*)(in + (size_t)srcs[i] * DD + lane * 2);
        a0 += unpackhl(p.x);
        a1 += unpackhl(p.y);
    }
    int deg = e - b;
    float inv = 1.0f / (float)(deg > 0 ? deg : 1);
    uint2 r;
    r.x = packhl(a0 * inv);
    r.y = packhl(a1 * inv);
    *(uint2*)(o + (size_t)node * DD + lane * 2) = r;
}

// ---------------------------------------------------------------------------
// Split-precision bf16 MFMA GEMM: C = relu([A1|A2] @ Bt^T + bias)
//   A1,A2: [NN,128] packed hi/lo (K-concat: k<128 -> A1, else A2)
//   Bt:    [128,256] hi/lo bf16, n-major (zero-padded rows n>=NC)
// Wave = 1 m-tile (16 rows) x NT n-tiles (NT=8 covers all 128 cols -> A read
// once). Block = 4 waves = 64 rows; grid = 782. Explicit 1-deep A prefetch.
template <int NT, bool PACKOUT>
__global__ void k_mfma(const unsigned int* __restrict__ A1p, const unsigned int* __restrict__ A2p,
                       const unsigned short* __restrict__ Bth, const unsigned short* __restrict__ Btl,
                       const float* __restrict__ bias, float* __restrict__ outf,
                       unsigned int* __restrict__ outp, const int NC) {
    const int tid = threadIdx.x;
    const int wave = tid >> 6, lane = tid & 63;
    const int quad = lane >> 4, mr = lane & 15;
    const int m0 = blockIdx.x * 64 + wave * 16;
    const int row = m0 + mr;
    const bool rok = row < NN;

    f32x4 acc[NT] = {};

    auto aload = [&](int ks, uint4& lo, uint4& hi) {
        const unsigned int* base = (ks < 4) ? A1p : A2p;
        const int ko = ((ks * 32) & 127) + quad * 8;
        if (rok) {
            const uint4* ap = (const uint4*)(base + (size_t)row * 128 + ko);
            lo = ap[0];
            hi = ap[1];
        } else {
            lo = make_uint4(0, 0, 0, 0);
            hi = make_uint4(0, 0, 0, 0);
        }
    };

    uint4 c0, c1, n0q, n1q;
    aload(0, c0, c1);
#pragma unroll
    for (int ks = 0; ks < 8; ++ks) {
        if (ks < 7) aload(ks + 1, n0q, n1q);  // prefetch next k-slice
        unsigned int u[8] = {c0.x, c0.y, c0.z, c0.w, c1.x, c1.y, c1.z, c1.w};
        bf8 ah, al;
#pragma unroll
        for (int j = 0; j < 8; ++j) {
            ah[j] = (short)(u[j] >> 16);
            al[j] = (short)(u[j] & 0xFFFFu);
        }
        const int kb = ks * 32;
#pragma unroll
        for (int n = 0; n < NT; ++n) {
            size_t boff = (size_t)(n * 16 + mr) * 256 + kb + quad * 8;
            bf8 bh = *(const bf8*)(Bth + boff);
            bf8 bl = *(const bf8*)(Btl + boff);
            acc[n] = __builtin_amdgcn_mfma_f32_16x16x32_bf16(ah, bh, acc[n], 0, 0, 0);
            acc[n] = __builtin_amdgcn_mfma_f32_16x16x32_bf16(al, bh, acc[n], 0, 0, 0);
            acc[n] = __builtin_amdgcn_mfma_f32_16x16x32_bf16(ah, bl, acc[n], 0, 0, 0);
        }
        c0 = n0q;
        c1 = n1q;
    }

    // Epilogue. C/D layout: col = lane&15, row = quad*4 + reg.
#pragma unroll
    for (int n = 0; n < NT; ++n) {
        int col = n * 16 + mr;
        float bv = (col < NC) ? bias[col] : 0.f;
#pragma unroll
        for (int r = 0; r < 4; ++r) {
            int orow = m0 + quad * 4 + r;
            if (orow < NN && col < NC) {
                float v = acc[n][r] + bv;
                v = v > 0.f ? v : 0.f;
                if (PACKOUT) {
                    outp[(size_t)orow * 128 + col] = packhl(v);
                } else {
                    outf[(size_t)orow * NC + col] = v;
                }
            }
        }
    }
}

// ---------------------------------------------------------------------------
extern "C" void kernel_launch(void* const* d_in, const int* in_sizes, int n_in,
                              void* d_out, int out_size, void* d_ws, size_t ws_size,
                              hipStream_t stream) {
    const float* x    = (const float*)d_in[0];
    const int*   ei   = (const int*)d_in[1];
    const float* w1_l = (const float*)d_in[2];
    const float* w1_r = (const float*)d_in[3];
    const float* b1   = (const float*)d_in[4];
    const float* w2_l = (const float*)d_in[5];
    const float* w2_r = (const float*)d_in[6];
    const float* b2   = (const float*)d_in[7];
    const float* w3_l = (const float*)d_in[8];
    const float* w3_r = (const float*)d_in[9];
    const float* b3   = (const float*)d_in[10];
    float* out = (float*)d_out;

    char* w = (char*)d_ws;
    size_t off = 0;
    auto alloc = [&](size_t bytes) -> void* {
        void* p = w + off;
        off += (bytes + 255) / 256 * 256;
        return p;
    };
    int* flag    = (int*)alloc(4);
    int* cnt     = (int*)alloc((size_t)NN * 4);
    int* row_ptr = (int*)alloc((size_t)(NN + 1) * 4);
    int* cursor  = (int*)alloc((size_t)NN * 4);
    int* srcs    = (int*)alloc((size_t)NE * 4);
    int* incl    = (int*)alloc((size_t)NN * 4);
    int* bsum    = (int*)alloc(64 * 4);
    int* boff    = (int*)alloc(64 * 4);
    unsigned int* xp   = (unsigned int*)alloc((size_t)NN * DD * 4);  // also h2p
    unsigned int* aggp = (unsigned int*)alloc((size_t)NN * DD * 4);
    unsigned int* h1p  = (unsigned int*)alloc((size_t)NN * DD * 4);
    unsigned short* bt1h = (unsigned short*)alloc(128 * 256 * 2);
    unsigned short* bt1l = (unsigned short*)alloc(128 * 256 * 2);
    unsigned short* bt2h = (unsigned short*)alloc(128 * 256 * 2);
    unsigned short* bt2l = (unsigned short*)alloc(128 * 256 * 2);
    unsigned short* bt3h = (unsigned short*)alloc(128 * 256 * 2);
    unsigned short* bt3l = (unsigned short*)alloc(128 * 256 * 2);
    unsigned int* h2p = xp;  // x dead after layer-1 GEMM
    (void)ws_size;

    const int eb = (NE + 255) / 256;
    const int nb = (NN + 1023) / 1024;  // 49
    k_zero_int<<<(NN + 255) / 256, 256, 0, stream>>>(cnt, NN);
    k_detect<<<1, 256, 0, stream>>>(ei, flag);
    k_count<<<eb, 256, 0, stream>>>(ei, flag, cnt);
    k_scan1<<<nb, 1024, 0, stream>>>(cnt, incl, bsum);
    k_scan2<<<1, 64, 0, stream>>>(bsum, boff, nb);
    k_scan3<<<nb, 1024, 0, stream>>>(cnt, incl, boff, row_ptr, cursor, nb);
    k_fill<<<eb, 256, 0, stream>>>(ei, flag, row_ptr, cursor, srcs);

    k_cvt_x<<<(NN * DD / 4) / 256, 256, 0, stream>>>(x, xp);
    k_cvt_w<<<128, 256, 0, stream>>>(w1_l, w1_r, bt1h, bt1l, DD);
    k_cvt_w<<<128, 256, 0, stream>>>(w2_l, w2_r, bt2h, bt2l, DD);
    k_cvt_w<<<128, 256, 0, stream>>>(w3_l, w3_r, bt3h, bt3l, NCLS);

    const int gmb = (NN + 63) / 64;   // 782 (GEMM m-blocks)
    const int gab = (NN + 3) / 4;     // 12500 (agg blocks, 4 nodes each)
    // Layer 1
    k_agg<<<gab, 256, 0, stream>>>(xp, row_ptr, srcs, aggp);
    k_mfma<8, true><<<gmb, 256, 0, stream>>>(aggp, xp, bt1h, bt1l, b1,
                                             nullptr, h1p, DD);
    // Layer 2 (h2p aliases xp; x is dead)
    k_agg<<<gab, 256, 0, stream>>>(h1p, row_ptr, srcs, aggp);
    k_mfma<8, true><<<gmb, 256, 0, stream>>>(aggp, h1p, bt2h, bt2l, b2,
                                             nullptr, h2p, DD);
    // Layer 3
    k_agg<<<gab, 256, 0, stream>>>(h2p, row_ptr, srcs, aggp);
    k_mfma<3, false><<<gmb, 256, 0, stream>>>(aggp, h2p, bt3h, bt3l, b3,
                                              out, nullptr, NCLS);
}

// Round 6
// 441.445 us; speedup vs baseline: 1.2305x; 1.2305x over previous
//
#include <hip/hip_runtime.h>
#include <hip/hip_bf16.h>

#define NN 50000
#define NE 800000
#define DD 128
#define NCLS 40

typedef short bf8 __attribute__((ext_vector_type(8)));   // 8 bf16 (4 VGPRs)
typedef float f32x4 __attribute__((ext_vector_type(4))); // MFMA acc

__device__ __forceinline__ unsigned short f2bf(float x) {
    unsigned int u = __float_as_uint(x);
    unsigned int r = (u + 0x7FFFu + ((u >> 16) & 1u)) >> 16;  // RNE
    return (unsigned short)r;
}
__device__ __forceinline__ float bf2f(unsigned short h) {
    return __uint_as_float(((unsigned int)h) << 16);
}
__device__ __forceinline__ unsigned int packhl(float v) {
    unsigned short h = f2bf(v);
    unsigned short l = f2bf(v - bf2f(h));
    return ((unsigned int)h << 16) | l;
}
__device__ __forceinline__ float unpackhl(unsigned int p) {
    return __uint_as_float(p & 0xFFFF0000u) + __uint_as_float(p << 16);
}

// ---------------------------------------------------------------------------
__global__ void k_detect(const int* __restrict__ ei, int* __restrict__ flag) {
    __shared__ int nz;
    if (threadIdx.x == 0) nz = 0;
    __syncthreads();
    int any = 0;
    for (int e = threadIdx.x; e < 2048; e += 256)
        if (ei[2 * e + 1] != 0) any = 1;
    if (any) atomicOr(&nz, 1);
    __syncthreads();
    if (threadIdx.x == 0) *flag = (nz == 0) ? 1 : 0;  // 1 => int64 layout
}

__global__ void k_zero_int(int* __restrict__ p, int n) {
    int i = blockIdx.x * 256 + threadIdx.x;
    if (i < n) p[i] = 0;
}

__global__ void k_count(const int* __restrict__ ei, const int* __restrict__ flag,
                        int* __restrict__ cnt) {
    int e = blockIdx.x * 256 + threadIdx.x;
    if (e >= NE) return;
    int is64 = *flag;
    int d = is64 ? ei[2 * (NE + e)] : ei[NE + e];
    atomicAdd(&cnt[d], 1);
}

__global__ void k_scan1(const int* __restrict__ cnt, int* __restrict__ incl,
                        int* __restrict__ bsum) {
    __shared__ int s[1024];
    int t = threadIdx.x;
    int i = blockIdx.x * 1024 + t;
    int v = (i < NN) ? cnt[i] : 0;
    s[t] = v;
    __syncthreads();
#pragma unroll
    for (int off = 1; off < 1024; off <<= 1) {
        int u = (t >= off) ? s[t - off] : 0;
        __syncthreads();
        s[t] += u;
        __syncthreads();
    }
    if (i < NN) incl[i] = s[t];
    if (t == 1023) bsum[blockIdx.x] = s[1023];
}

__global__ void k_scan2(int* __restrict__ bsum, int* __restrict__ boff,
                        const int nb) {
    __shared__ int s[64];
    int t = threadIdx.x;
    s[t] = (t < nb) ? bsum[t] : 0;
    __syncthreads();
#pragma unroll
    for (int off = 1; off < 64; off <<= 1) {
        int u = (t >= off) ? s[t - off] : 0;
        __syncthreads();
        s[t] += u;
        __syncthreads();
    }
    if (t < nb) boff[t] = s[t] - bsum[t];
    if (t == 63) boff[nb] = s[63];
}

__global__ void k_scan3(const int* __restrict__ cnt, const int* __restrict__ incl,
                        const int* __restrict__ boff, int* __restrict__ row_ptr,
                        int* __restrict__ cursor, const int nb) {
    int i = blockIdx.x * 1024 + threadIdx.x;
    if (i < NN) {
        row_ptr[i] = incl[i] - cnt[i] + boff[blockIdx.x];
        cursor[i] = 0;
    }
    if (i == 0) row_ptr[NN] = boff[nb];
}

__global__ void k_fill(const int* __restrict__ ei, const int* __restrict__ flag,
                       const int* __restrict__ row_ptr, int* __restrict__ cursor,
                       int* __restrict__ srcs) {
    int e = blockIdx.x * 256 + threadIdx.x;
    if (e >= NE) return;
    int is64 = *flag;
    int s, d;
    if (is64) { s = ei[2 * e]; d = ei[2 * (NE + e)]; }
    else      { s = ei[e];     d = ei[NE + e]; }
    int pos = row_ptr[d] + atomicAdd(&cursor[d], 1);
    srcs[pos] = s;
}

// ---------------------------------------------------------------------------
// fp32 -> packed (hi<<16 | lo). 50000*128/4 float4 -> uint4.
__global__ void k_cvt_x(const float* __restrict__ x, unsigned int* __restrict__ xp) {
    int i = blockIdx.x * 256 + threadIdx.x;
    float4 v = ((const float4*)x)[i];
    uint4 o;
    o.x = packhl(v.x); o.y = packhl(v.y); o.z = packhl(v.z); o.w = packhl(v.w);
    ((uint4*)xp)[i] = o;
}

// Build B in MFMA-fragment-major order: elem((ks, nt, lane, j)) =
//   Bt[nt*16 + (lane&15)][ks*32 + (lane>>4)*8 + j],  Bt[n][k] over [Wl;Wr].
// grid = (8 ks, NT); block = (8 j, 64 lane). Zero-pad n >= NC.
__global__ void k_cvt_wf(const float* __restrict__ wl, const float* __restrict__ wr,
                         unsigned short* __restrict__ bthf, unsigned short* __restrict__ btlf,
                         const int NC, const int NT) {
    int ks = blockIdx.x, nt = blockIdx.y;
    int lane = threadIdx.y, j = threadIdx.x;
    int row = nt * 16 + (lane & 15);          // output column n
    int k = ks * 32 + (lane >> 4) * 8 + j;    // K position in [Wl;Wr]
    float v = 0.f;
    if (row < NC)
        v = (k < 128) ? wl[(size_t)k * NC + row] : wr[(size_t)(k - 128) * NC + row];
    unsigned short h = f2bf(v);
    unsigned short l = f2bf(v - bf2f(h));
    size_t o = ((size_t)(ks * NT + nt) * 64 + lane) * 8 + j;
    bthf[o] = h;
    btlf[o] = l;
}

// ---------------------------------------------------------------------------
// Mean aggregation: one wave per node, uint2 per lane (full 512B row/neighbor).
__global__ void k_agg(const unsigned int* __restrict__ in, const int* __restrict__ row_ptr,
                      const int* __restrict__ srcs, unsigned int* __restrict__ o) {
    int node = blockIdx.x * 4 + (threadIdx.x >> 6);
    if (node >= NN) return;
    int lane = threadIdx.x & 63;
    int b = row_ptr[node], e = row_ptr[node + 1];
    float a0 = 0.f, a1 = 0.f;
    int i = b;
    for (; i + 3 < e; i += 4) {
        int s0 = srcs[i + 0], s1 = srcs[i + 1], s2 = srcs[i + 2], s3 = srcs[i + 3];
        uint2 p0 = *(const uint2*)(in + (size_t)s0 * DD + lane * 2);
        uint2 p1 = *(const uint2*)(in + (size_t)s1 * DD + lane * 2);
        uint2 p2 = *(const uint2*)(in + (size_t)s2 * DD + lane * 2);
        uint2 p3 = *(const uint2*)(in + (size_t)s3 * DD + lane * 2);
        a0 += unpackhl(p0.x) + unpackhl(p1.x) + unpackhl(p2.x) + unpackhl(p3.x);
        a1 += unpackhl(p0.y) + unpackhl(p1.y) + unpackhl(p2.y) + unpackhl(p3.y);
    }
    for (; i < e; ++i) {
        uint2 p = *(const uint2*)(in + (size_t)srcs[i] * DD + lane * 2);
        a0 += unpackhl(p.x);
        a1 += unpackhl(p.y);
    }
    int deg = e - b;
    float inv = 1.0f / (float)(deg > 0 ? deg : 1);
    uint2 r;
    r.x = packhl(a0 * inv);
    r.y = packhl(a1 * inv);
    *(uint2*)(o + (size_t)node * DD + lane * 2) = r;
}

// ---------------------------------------------------------------------------
// Split-precision bf16 MFMA GEMM, B staged in LDS in fragment layout.
//   A1,A2: [NN,128] packed hi/lo (K-concat: k<128 -> A1, else A2)
//   Bthf/Btlf: fragment-major [(ks*NT+nt)*64+lane]*8+j
// Wave = 1 m-tile (16 rows) x NT n-tiles; block = 4 waves = 64 rows.
// K-loop split into 8/KPS stages; per stage, B (hi+lo) cooperatively copied
// into LDS, inner reads are contiguous ds_read_b128. A: 1-deep global prefetch.
template <int NT, int KPS, bool PACKOUT>
__launch_bounds__(256, 4)
__global__ void k_mfma(const unsigned int* __restrict__ A1p, const unsigned int* __restrict__ A2p,
                       const unsigned short* __restrict__ Bthf, const unsigned short* __restrict__ Btlf,
                       const float* __restrict__ bias, float* __restrict__ outf,
                       unsigned int* __restrict__ outp, const int NC) {
    constexpr int STAGE_ELEMS = KPS * NT * 64 * 8;          // bf16 per stage
    constexpr int STAGE_U4 = STAGE_ELEMS / 8;               // uint4 per stage
    constexpr int COPIES = STAGE_U4 / 256;                  // per-thread uint4
    __shared__ unsigned short sBh[STAGE_ELEMS];
    __shared__ unsigned short sBl[STAGE_ELEMS];

    const int tid = threadIdx.x;
    const int wave = tid >> 6, lane = tid & 63;
    const int quad = lane >> 4, mr = lane & 15;
    const int m0 = blockIdx.x * 64 + wave * 16;
    const int row = m0 + mr;
    const bool rok = row < NN;

    f32x4 acc[NT] = {};

    auto aload = [&](int ks, uint4& lo, uint4& hi) {
        const unsigned int* base = (ks < 4) ? A1p : A2p;
        const int ko = ((ks * 32) & 127) + quad * 8;
        if (rok) {
            const uint4* ap = (const uint4*)(base + (size_t)row * 128 + ko);
            lo = ap[0];
            hi = ap[1];
        } else {
            lo = make_uint4(0, 0, 0, 0);
            hi = make_uint4(0, 0, 0, 0);
        }
    };

    uint4 c0, c1, p0q, p1q;
    aload(0, c0, c1);

#pragma unroll
    for (int s = 0; s < 8 / KPS; ++s) {
        // ---- stage B (hi+lo) into LDS, coalesced uint4 copies
        const uint4* gh = (const uint4*)(Bthf + (size_t)s * STAGE_ELEMS);
        const uint4* gl = (const uint4*)(Btlf + (size_t)s * STAGE_ELEMS);
        uint4* lh = (uint4*)sBh;
        uint4* ll = (uint4*)sBl;
        if (s) __syncthreads();  // previous stage fully consumed
#pragma unroll
        for (int i = 0; i < COPIES; ++i) {
            lh[tid + i * 256] = gh[tid + i * 256];
            ll[tid + i * 256] = gl[tid + i * 256];
        }
        __syncthreads();

#pragma unroll
        for (int kl = 0; kl < KPS; ++kl) {
            const int ks = s * KPS + kl;
            if (ks < 7) aload(ks + 1, p0q, p1q);  // prefetch next A slice
            unsigned int u[8] = {c0.x, c0.y, c0.z, c0.w, c1.x, c1.y, c1.z, c1.w};
            bf8 ah, al;
#pragma unroll
            for (int j = 0; j < 8; ++j) {
                ah[j] = (short)(u[j] >> 16);
                al[j] = (short)(u[j] & 0xFFFFu);
            }
#pragma unroll
            for (int n = 0; n < NT; ++n) {
                const int fo = ((kl * NT + n) * 64 + lane) * 8;
                bf8 bh = *(const bf8*)(sBh + fo);
                bf8 bl = *(const bf8*)(sBl + fo);
                acc[n] = __builtin_amdgcn_mfma_f32_16x16x32_bf16(ah, bh, acc[n], 0, 0, 0);
                acc[n] = __builtin_amdgcn_mfma_f32_16x16x32_bf16(al, bh, acc[n], 0, 0, 0);
                acc[n] = __builtin_amdgcn_mfma_f32_16x16x32_bf16(ah, bl, acc[n], 0, 0, 0);
            }
            c0 = p0q;
            c1 = p1q;
        }
    }

    // Epilogue. C/D layout: col = lane&15, row = quad*4 + reg.
#pragma unroll
    for (int n = 0; n < NT; ++n) {
        int col = n * 16 + mr;
        float bv = (col < NC) ? bias[col] : 0.f;
#pragma unroll
        for (int r = 0; r < 4; ++r) {
            int orow = m0 + quad * 4 + r;
            if (orow < NN && col < NC) {
                float v = acc[n][r] + bv;
                v = v > 0.f ? v : 0.f;
                if (PACKOUT) {
                    outp[(size_t)orow * 128 + col] = packhl(v);
                } else {
                    outf[(size_t)orow * NC + col] = v;
                }
            }
        }
    }
}

// ---------------------------------------------------------------------------
extern "C" void kernel_launch(void* const* d_in, const int* in_sizes, int n_in,
                              void* d_out, int out_size, void* d_ws, size_t ws_size,
                              hipStream_t stream) {
    const float* x    = (const float*)d_in[0];
    const int*   ei   = (const int*)d_in[1];
    const float* w1_l = (const float*)d_in[2];
    const float* w1_r = (const float*)d_in[3];
    const float* b1   = (const float*)d_in[4];
    const float* w2_l = (const float*)d_in[5];
    const float* w2_r = (const float*)d_in[6];
    const float* b2   = (const float*)d_in[7];
    const float* w3_l = (const float*)d_in[8];
    const float* w3_r = (const float*)d_in[9];
    const float* b3   = (const float*)d_in[10];
    float* out = (float*)d_out;

    char* w = (char*)d_ws;
    size_t off = 0;
    auto alloc = [&](size_t bytes) -> void* {
        void* p = w + off;
        off += (bytes + 255) / 256 * 256;
        return p;
    };
    int* flag    = (int*)alloc(4);
    int* cnt     = (int*)alloc((size_t)NN * 4);
    int* row_ptr = (int*)alloc((size_t)(NN + 1) * 4);
    int* cursor  = (int*)alloc((size_t)NN * 4);
    int* srcs    = (int*)alloc((size_t)NE * 4);
    int* incl    = (int*)alloc((size_t)NN * 4);
    int* bsum    = (int*)alloc(64 * 4);
    int* boff    = (int*)alloc(64 * 4);
    unsigned int* xp   = (unsigned int*)alloc((size_t)NN * DD * 4);  // also h2p
    unsigned int* aggp = (unsigned int*)alloc((size_t)NN * DD * 4);
    unsigned int* h1p  = (unsigned int*)alloc((size_t)NN * DD * 4);
    unsigned short* bt1h = (unsigned short*)alloc((size_t)8 * 8 * 64 * 8 * 2);
    unsigned short* bt1l = (unsigned short*)alloc((size_t)8 * 8 * 64 * 8 * 2);
    unsigned short* bt2h = (unsigned short*)alloc((size_t)8 * 8 * 64 * 8 * 2);
    unsigned short* bt2l = (unsigned short*)alloc((size_t)8 * 8 * 64 * 8 * 2);
    unsigned short* bt3h = (unsigned short*)alloc((size_t)8 * 3 * 64 * 8 * 2);
    unsigned short* bt3l = (unsigned short*)alloc((size_t)8 * 3 * 64 * 8 * 2);
    unsigned int* h2p = xp;  // x dead after layer-1 GEMM
    (void)ws_size;

    const int eb = (NE + 255) / 256;
    const int nb = (NN + 1023) / 1024;  // 49
    k_zero_int<<<(NN + 255) / 256, 256, 0, stream>>>(cnt, NN);
    k_detect<<<1, 256, 0, stream>>>(ei, flag);
    k_count<<<eb, 256, 0, stream>>>(ei, flag, cnt);
    k_scan1<<<nb, 1024, 0, stream>>>(cnt, incl, bsum);
    k_scan2<<<1, 64, 0, stream>>>(bsum, boff, nb);
    k_scan3<<<nb, 1024, 0, stream>>>(cnt, incl, boff, row_ptr, cursor, nb);
    k_fill<<<eb, 256, 0, stream>>>(ei, flag, row_ptr, cursor, srcs);

    k_cvt_x<<<(NN * DD / 4) / 256, 256, 0, stream>>>(x, xp);
    k_cvt_wf<<<dim3(8, 8), dim3(8, 64), 0, stream>>>(w1_l, w1_r, bt1h, bt1l, DD, 8);
    k_cvt_wf<<<dim3(8, 8), dim3(8, 64), 0, stream>>>(w2_l, w2_r, bt2h, bt2l, DD, 8);
    k_cvt_wf<<<dim3(8, 3), dim3(8, 64), 0, stream>>>(w3_l, w3_r, bt3h, bt3l, NCLS, 3);

    const int gmb = (NN + 63) / 64;   // 782 (GEMM m-blocks)
    const int gab = (NN + 3) / 4;     // 12500 (agg blocks, 4 nodes each)
    // Layer 1
    k_agg<<<gab, 256, 0, stream>>>(xp, row_ptr, srcs, aggp);
    k_mfma<8, 4, true><<<gmb, 256, 0, stream>>>(aggp, xp, bt1h, bt1l, b1,
                                                nullptr, h1p, DD);
    // Layer 2 (h2p aliases xp; x is dead)
    k_agg<<<gab, 256, 0, stream>>>(h1p, row_ptr, srcs, aggp);
    k_mfma<8, 4, true><<<gmb, 256, 0, stream>>>(aggp, h1p, bt2h, bt2l, b2,
                                                nullptr, h2p, DD);
    // Layer 3
    k_agg<<<gab, 256, 0, stream>>>(h2p, row_ptr, srcs, aggp);
    k_mfma<3, 8, false><<<gmb, 256, 0, stream>>>(aggp, h2p, bt3h, bt3l, b3,
                                                 out, nullptr, NCLS);
}

// Round 7
// 378.321 us; speedup vs baseline: 1.4358x; 1.1669x over previous
//
#include <hip/hip_runtime.h>
#include <hip/hip_bf16.h>

#define NN 50000
#define NE 800000
#define DD 128
#define NCLS 40

typedef _Float16 f16x8 __attribute__((ext_vector_type(8)));  // 8 f16 (4 VGPRs)
typedef _Float16 f16x4 __attribute__((ext_vector_type(4)));
typedef float f32x4 __attribute__((ext_vector_type(4)));     // MFMA acc

__device__ __forceinline__ unsigned int pack2h(_Float16 a, _Float16 b) {
    union { _Float16 h[2]; unsigned int u; } c;
    c.h[0] = a; c.h[1] = b;
    return c.u;
}
__device__ __forceinline__ void unpack2h(unsigned int p, float& a, float& b) {
    union { unsigned int u; _Float16 h[2]; } c;
    c.u = p;
    a = (float)c.h[0]; b = (float)c.h[1];
}

// ---------------------------------------------------------------------------
__global__ void k_detect(const int* __restrict__ ei, int* __restrict__ flag) {
    __shared__ int nz;
    if (threadIdx.x == 0) nz = 0;
    __syncthreads();
    int any = 0;
    for (int e = threadIdx.x; e < 2048; e += 256)
        if (ei[2 * e + 1] != 0) any = 1;
    if (any) atomicOr(&nz, 1);
    __syncthreads();
    if (threadIdx.x == 0) *flag = (nz == 0) ? 1 : 0;  // 1 => int64 layout
}

__global__ void k_zero_int(int* __restrict__ p, int n) {
    int i = blockIdx.x * 256 + threadIdx.x;
    if (i < n) p[i] = 0;
}

__global__ void k_count(const int* __restrict__ ei, const int* __restrict__ flag,
                        int* __restrict__ cnt) {
    int e = blockIdx.x * 256 + threadIdx.x;
    if (e >= NE) return;
    int is64 = *flag;
    int d = is64 ? ei[2 * (NE + e)] : ei[NE + e];
    atomicAdd(&cnt[d], 1);
}

__global__ void k_scan1(const int* __restrict__ cnt, int* __restrict__ incl,
                        int* __restrict__ bsum) {
    __shared__ int s[1024];
    int t = threadIdx.x;
    int i = blockIdx.x * 1024 + t;
    int v = (i < NN) ? cnt[i] : 0;
    s[t] = v;
    __syncthreads();
#pragma unroll
    for (int off = 1; off < 1024; off <<= 1) {
        int u = (t >= off) ? s[t - off] : 0;
        __syncthreads();
        s[t] += u;
        __syncthreads();
    }
    if (i < NN) incl[i] = s[t];
    if (t == 1023) bsum[blockIdx.x] = s[1023];
}

__global__ void k_scan2(int* __restrict__ bsum, int* __restrict__ boff,
                        const int nb) {
    __shared__ int s[64];
    int t = threadIdx.x;
    s[t] = (t < nb) ? bsum[t] : 0;
    __syncthreads();
#pragma unroll
    for (int off = 1; off < 64; off <<= 1) {
        int u = (t >= off) ? s[t - off] : 0;
        __syncthreads();
        s[t] += u;
        __syncthreads();
    }
    if (t < nb) boff[t] = s[t] - bsum[t];
    if (t == 63) boff[nb] = s[63];
}

__global__ void k_scan3(const int* __restrict__ cnt, const int* __restrict__ incl,
                        const int* __restrict__ boff, int* __restrict__ row_ptr,
                        int* __restrict__ cursor, const int nb) {
    int i = blockIdx.x * 1024 + threadIdx.x;
    if (i < NN) {
        row_ptr[i] = incl[i] - cnt[i] + boff[blockIdx.x];
        cursor[i] = 0;
    }
    if (i == 0) row_ptr[NN] = boff[nb];
}

__global__ void k_fill(const int* __restrict__ ei, const int* __restrict__ flag,
                       const int* __restrict__ row_ptr, int* __restrict__ cursor,
                       int* __restrict__ srcs) {
    int e = blockIdx.x * 256 + threadIdx.x;
    if (e >= NE) return;
    int is64 = *flag;
    int s, d;
    if (is64) { s = ei[2 * e]; d = ei[2 * (NE + e)]; }
    else      { s = ei[e];     d = ei[NE + e]; }
    int pos = row_ptr[d] + atomicAdd(&cursor[d], 1);
    srcs[pos] = s;
}

// ---------------------------------------------------------------------------
// fp32 -> f16 hi/lo planes. Each thread: 4 features (float4 -> 2x f16x4).
__global__ void k_cvt_x(const float* __restrict__ x, unsigned short* __restrict__ xh,
                        unsigned short* __restrict__ xl) {
    int i = blockIdx.x * 256 + threadIdx.x;
    float4 v = ((const float4*)x)[i];
    float f[4] = {v.x, v.y, v.z, v.w};
    f16x4 h, l;
#pragma unroll
    for (int j = 0; j < 4; ++j) {
        _Float16 hh = (_Float16)f[j];
        h[j] = hh;
        l[j] = (_Float16)(f[j] - (float)hh);
    }
    *(f16x4*)(xh + (size_t)i * 4) = h;
    *(f16x4*)(xl + (size_t)i * 4) = l;
}

// Build B in MFMA-fragment-major order (f16 hi/lo planes):
//   elem((ks,nt,lane,j)) = Bt[nt*16+(lane&15)][ks*32+(lane>>4)*8+j]
__global__ void k_cvt_wf(const float* __restrict__ wl, const float* __restrict__ wr,
                         unsigned short* __restrict__ bthf, unsigned short* __restrict__ btlf,
                         const int NC, const int NT) {
    int ks = blockIdx.x, nt = blockIdx.y;
    int lane = threadIdx.y, j = threadIdx.x;
    int row = nt * 16 + (lane & 15);          // output column n
    int k = ks * 32 + (lane >> 4) * 8 + j;    // K position in [Wl;Wr]
    float v = 0.f;
    if (row < NC)
        v = (k < 128) ? wl[(size_t)k * NC + row] : wr[(size_t)(k - 128) * NC + row];
    _Float16 h = (_Float16)v;
    _Float16 l = (_Float16)(v - (float)h);
    size_t o = ((size_t)(ks * NT + nt) * 64 + lane) * 8 + j;
    union { _Float16 f; unsigned short u; } ch, cl;
    ch.f = h; cl.f = l;
    bthf[o] = ch.u;
    btlf[o] = cl.u;
}

// ---------------------------------------------------------------------------
// Mean aggregation, hi-plane only: one wave per node, 1 uint (2 f16) per lane.
// 256-thread block covers 4 nodes.
__global__ void k_agg(const unsigned int* __restrict__ inh, const int* __restrict__ row_ptr,
                      const int* __restrict__ srcs, unsigned int* __restrict__ oh,
                      unsigned int* __restrict__ ol) {
    int node = blockIdx.x * 4 + (threadIdx.x >> 6);
    if (node >= NN) return;
    int lane = threadIdx.x & 63;
    int b = row_ptr[node], e = row_ptr[node + 1];
    float a0 = 0.f, a1 = 0.f;
    int i = b;
    for (; i + 3 < e; i += 4) {
        int s0 = srcs[i + 0], s1 = srcs[i + 1], s2 = srcs[i + 2], s3 = srcs[i + 3];
        unsigned int p0 = inh[(size_t)s0 * 64 + lane];
        unsigned int p1 = inh[(size_t)s1 * 64 + lane];
        unsigned int p2 = inh[(size_t)s2 * 64 + lane];
        unsigned int p3 = inh[(size_t)s3 * 64 + lane];
        float u0, u1;
        unpack2h(p0, u0, u1); a0 += u0; a1 += u1;
        unpack2h(p1, u0, u1); a0 += u0; a1 += u1;
        unpack2h(p2, u0, u1); a0 += u0; a1 += u1;
        unpack2h(p3, u0, u1); a0 += u0; a1 += u1;
    }
    for (; i < e; ++i) {
        unsigned int p = inh[(size_t)srcs[i] * 64 + lane];
        float u0, u1;
        unpack2h(p, u0, u1); a0 += u0; a1 += u1;
    }
    int deg = e - b;
    float inv = 1.0f / (float)(deg > 0 ? deg : 1);
    float v0 = a0 * inv, v1 = a1 * inv;
    _Float16 h0 = (_Float16)v0, h1 = (_Float16)v1;
    oh[(size_t)node * 64 + lane] = pack2h(h0, h1);
    ol[(size_t)node * 64 + lane] = pack2h((_Float16)(v0 - (float)h0),
                                          (_Float16)(v1 - (float)h1));
}

// ---------------------------------------------------------------------------
// Split-precision f16 MFMA GEMM, B staged in LDS in fragment layout.
//   A1 (agg) / A2 (self): f16 hi/lo planes [NN][128]
//   Bthf/Btlf: fragment-major f16 planes
// Wave = 1 m-tile (16 rows) x NT n-tiles; block = 4 waves = 64 rows.
// 3-product split: Ah*Bh + Al*Bh + Ah*Bl (~2^-21 rel).
template <int NT, int KPS, bool PACKOUT>
__launch_bounds__(256, 4)
__global__ void k_mfma(const unsigned short* __restrict__ A1h, const unsigned short* __restrict__ A1l,
                       const unsigned short* __restrict__ A2h, const unsigned short* __restrict__ A2l,
                       const unsigned short* __restrict__ Bthf, const unsigned short* __restrict__ Btlf,
                       const float* __restrict__ bias, float* __restrict__ outf,
                       unsigned short* __restrict__ outh, unsigned short* __restrict__ outl,
                       const int NC) {
    constexpr int STAGE_ELEMS = KPS * NT * 64 * 8;          // f16 per stage
    constexpr int STAGE_U4 = STAGE_ELEMS / 8;               // uint4 per stage
    constexpr int COPIES = STAGE_U4 / 256;                  // per-thread uint4
    __shared__ unsigned short sBh[STAGE_ELEMS];
    __shared__ unsigned short sBl[STAGE_ELEMS];

    const int tid = threadIdx.x;
    const int wave = tid >> 6, lane = tid & 63;
    const int quad = lane >> 4, mr = lane & 15;
    const int m0 = blockIdx.x * 64 + wave * 16;
    const int row = m0 + mr;
    const bool rok = row < NN;

    f32x4 acc[NT] = {};
    const f16x8 zero = {};

    auto aload = [&](int ks, f16x8& ah, f16x8& al) {
        const unsigned short* bh = (ks < 4) ? A1h : A2h;
        const unsigned short* bl = (ks < 4) ? A1l : A2l;
        const int ko = ((ks * 32) & 127) + quad * 8;
        if (rok) {
            ah = *(const f16x8*)(bh + (size_t)row * 128 + ko);
            al = *(const f16x8*)(bl + (size_t)row * 128 + ko);
        } else {
            ah = zero;
            al = zero;
        }
    };

    f16x8 cah, cal, pah, pal;
    aload(0, cah, cal);

#pragma unroll
    for (int s = 0; s < 8 / KPS; ++s) {
        // ---- stage B (hi+lo) into LDS, coalesced uint4 copies
        const uint4* gh = (const uint4*)(Bthf + (size_t)s * STAGE_ELEMS);
        const uint4* gl = (const uint4*)(Btlf + (size_t)s * STAGE_ELEMS);
        uint4* lh = (uint4*)sBh;
        uint4* ll = (uint4*)sBl;
        if (s) __syncthreads();
#pragma unroll
        for (int i = 0; i < COPIES; ++i) {
            lh[tid + i * 256] = gh[tid + i * 256];
            ll[tid + i * 256] = gl[tid + i * 256];
        }
        __syncthreads();

#pragma unroll
        for (int kl = 0; kl < KPS; ++kl) {
            const int ks = s * KPS + kl;
            if (ks < 7) aload(ks + 1, pah, pal);  // prefetch next A slice
#pragma unroll
            for (int n = 0; n < NT; ++n) {
                const int fo = ((kl * NT + n) * 64 + lane) * 8;
                f16x8 bh = *(const f16x8*)(sBh + fo);
                f16x8 bl = *(const f16x8*)(sBl + fo);
                acc[n] = __builtin_amdgcn_mfma_f32_16x16x32_f16(cah, bh, acc[n], 0, 0, 0);
                acc[n] = __builtin_amdgcn_mfma_f32_16x16x32_f16(cal, bh, acc[n], 0, 0, 0);
                acc[n] = __builtin_amdgcn_mfma_f32_16x16x32_f16(cah, bl, acc[n], 0, 0, 0);
            }
            cah = pah;
            cal = pal;
        }
    }

    // Epilogue. C/D layout: col = lane&15, row = quad*4 + reg.
#pragma unroll
    for (int n = 0; n < NT; ++n) {
        int col = n * 16 + mr;
        float bv = (col < NC) ? bias[col] : 0.f;
#pragma unroll
        for (int r = 0; r < 4; ++r) {
            int orow = m0 + quad * 4 + r;
            if (orow < NN && col < NC) {
                float v = acc[n][r] + bv;
                v = v > 0.f ? v : 0.f;
                if (PACKOUT) {
                    _Float16 h = (_Float16)v;
                    _Float16 l = (_Float16)(v - (float)h);
                    union { _Float16 f; unsigned short u; } ch, cl;
                    ch.f = h; cl.f = l;
                    outh[(size_t)orow * 128 + col] = ch.u;
                    outl[(size_t)orow * 128 + col] = cl.u;
                } else {
                    outf[(size_t)orow * NC + col] = v;
                }
            }
        }
    }
}

// ---------------------------------------------------------------------------
extern "C" void kernel_launch(void* const* d_in, const int* in_sizes, int n_in,
                              void* d_out, int out_size, void* d_ws, size_t ws_size,
                              hipStream_t stream) {
    const float* x    = (const float*)d_in[0];
    const int*   ei   = (const int*)d_in[1];
    const float* w1_l = (const float*)d_in[2];
    const float* w1_r = (const float*)d_in[3];
    const float* b1   = (const float*)d_in[4];
    const float* w2_l = (const float*)d_in[5];
    const float* w2_r = (const float*)d_in[6];
    const float* b2   = (const float*)d_in[7];
    const float* w3_l = (const float*)d_in[8];
    const float* w3_r = (const float*)d_in[9];
    const float* b3   = (const float*)d_in[10];
    float* out = (float*)d_out;

    char* w = (char*)d_ws;
    size_t off = 0;
    auto alloc = [&](size_t bytes) -> void* {
        void* p = w + off;
        off += (bytes + 255) / 256 * 256;
        return p;
    };
    int* flag    = (int*)alloc(4);
    int* cnt     = (int*)alloc((size_t)NN * 4);
    int* row_ptr = (int*)alloc((size_t)(NN + 1) * 4);
    int* cursor  = (int*)alloc((size_t)NN * 4);
    int* srcs    = (int*)alloc((size_t)NE * 4);
    int* incl    = (int*)alloc((size_t)NN * 4);
    int* bsum    = (int*)alloc(64 * 4);
    int* boff    = (int*)alloc(64 * 4);
    unsigned short* xh   = (unsigned short*)alloc((size_t)NN * DD * 2);  // also h2h
    unsigned short* xl   = (unsigned short*)alloc((size_t)NN * DD * 2);  // also h2l
    unsigned short* aggh = (unsigned short*)alloc((size_t)NN * DD * 2);
    unsigned short* aggl = (unsigned short*)alloc((size_t)NN * DD * 2);
    unsigned short* h1h  = (unsigned short*)alloc((size_t)NN * DD * 2);
    unsigned short* h1l  = (unsigned short*)alloc((size_t)NN * DD * 2);
    unsigned short* bt1h = (unsigned short*)alloc((size_t)8 * 8 * 64 * 8 * 2);
    unsigned short* bt1l = (unsigned short*)alloc((size_t)8 * 8 * 64 * 8 * 2);
    unsigned short* bt2h = (unsigned short*)alloc((size_t)8 * 8 * 64 * 8 * 2);
    unsigned short* bt2l = (unsigned short*)alloc((size_t)8 * 8 * 64 * 8 * 2);
    unsigned short* bt3h = (unsigned short*)alloc((size_t)8 * 3 * 64 * 8 * 2);
    unsigned short* bt3l = (unsigned short*)alloc((size_t)8 * 3 * 64 * 8 * 2);
    unsigned short* h2h = xh, *h2l = xl;  // x dead after layer-1 GEMM
    (void)ws_size;

    const int eb = (NE + 255) / 256;
    const int nb = (NN + 1023) / 1024;  // 49
    k_zero_int<<<(NN + 255) / 256, 256, 0, stream>>>(cnt, NN);
    k_detect<<<1, 256, 0, stream>>>(ei, flag);
    k_count<<<eb, 256, 0, stream>>>(ei, flag, cnt);
    k_scan1<<<nb, 1024, 0, stream>>>(cnt, incl, bsum);
    k_scan2<<<1, 64, 0, stream>>>(bsum, boff, nb);
    k_scan3<<<nb, 1024, 0, stream>>>(cnt, incl, boff, row_ptr, cursor, nb);
    k_fill<<<eb, 256, 0, stream>>>(ei, flag, row_ptr, cursor, srcs);

    k_cvt_x<<<(NN * DD / 4) / 256, 256, 0, stream>>>(x, xh, xl);
    k_cvt_wf<<<dim3(8, 8), dim3(8, 64), 0, stream>>>(w1_l, w1_r, bt1h, bt1l, DD, 8);
    k_cvt_wf<<<dim3(8, 8), dim3(8, 64), 0, stream>>>(w2_l, w2_r, bt2h, bt2l, DD, 8);
    k_cvt_wf<<<dim3(8, 3), dim3(8, 64), 0, stream>>>(w3_l, w3_r, bt3h, bt3l, NCLS, 3);

    const int gmb = (NN + 63) / 64;   // 782 (GEMM m-blocks)
    const int gab = (NN + 3) / 4;     // 12500 (agg blocks, 4 nodes each)
    // Layer 1
    k_agg<<<gab, 256, 0, stream>>>((const unsigned int*)xh, row_ptr, srcs,
                                   (unsigned int*)aggh, (unsigned int*)aggl);
    k_mfma<8, 4, true><<<gmb, 256, 0, stream>>>(aggh, aggl, xh, xl, bt1h, bt1l, b1,
                                                nullptr, h1h, h1l, DD);
    // Layer 2 (h2 planes alias x planes; x is dead)
    k_agg<<<gab, 256, 0, stream>>>((const unsigned int*)h1h, row_ptr, srcs,
                                   (unsigned int*)aggh, (unsigned int*)aggl);
    k_mfma<8, 4, true><<<gmb, 256, 0, stream>>>(aggh, aggl, h1h, h1l, bt2h, bt2l, b2,
                                                nullptr, h2h, h2l, DD);
    // Layer 3
    k_agg<<<gab, 256, 0, stream>>>((const unsigned int*)h2h, row_ptr, srcs,
                                   (unsigned int*)aggh, (unsigned int*)aggl);
    k_mfma<3, 8, false><<<gmb, 256, 0, stream>>>(aggh, aggl, h2h, h2l, bt3h, bt3l, b3,
                                                 out, nullptr, nullptr, NCLS);
}